// Round 4
// baseline (266.684 us; speedup 1.0000x reference)
//
#include <hip/hip_runtime.h>

#define HEADS 16
#define DK 64
#define DM 1024
#define SEQ 2048
#define BATCH 2

using bf16x8 = __attribute__((ext_vector_type(8))) short;
using short4v = __attribute__((ext_vector_type(4))) short;
using f32x4 = __attribute__((ext_vector_type(4))) float;

// fp32 -> bf16 bits, round-to-nearest-even (fallback path)
static __device__ __forceinline__ short f2bf(float x) {
  union { float f; unsigned u; } c;
  c.f = x;
  unsigned r = (c.u + 0x7FFFu + ((c.u >> 16) & 1u)) >> 16;
  return (short)r;
}

// pack two fp32 -> 2xbf16 in one u32 (lo = first). gfx950 has
// v_cvt_pk_bf16_f32 (RNE); fall back to bit-twiddle if builtin absent.
static __device__ __forceinline__ unsigned pk2bf(float lo, float hi) {
#if __has_builtin(__builtin_amdgcn_cvt_pk_bf16_f32)
  auto t = __builtin_amdgcn_cvt_pk_bf16_f32(lo, hi);
  if constexpr (sizeof(t) == 4) {
    unsigned u;
    __builtin_memcpy(&u, &t, 4);
    return u;
  } else {
    return (unsigned)(unsigned short)f2bf(lo) |
           ((unsigned)(unsigned short)f2bf(hi) << 16);
  }
#else
  return (unsigned)(unsigned short)f2bf(lo) |
         ((unsigned)(unsigned short)f2bf(hi) << 16);
#endif
}

// async global->LDS, 16B per lane; LDS dest is wave-uniform base + lane*16
static __device__ __forceinline__ void gload_lds16(const void* g, void* l) {
  __builtin_amdgcn_global_load_lds(
      (const __attribute__((address_space(1))) void*)g,
      (__attribute__((address_space(3))) void*)l, 16, 0, 0);
}

// ---------------------------------------------------------------------------
// Bulk fp32 -> bf16 conversion for q,k,v and the 4 weight matrices.
// ---------------------------------------------------------------------------
__global__ __launch_bounds__(256) void cvt7(
    const float* __restrict__ s0, const float* __restrict__ s1,
    const float* __restrict__ s2, const float* __restrict__ s3,
    const float* __restrict__ s4, const float* __restrict__ s5,
    const float* __restrict__ s6, short* d0, short* d1, short* d2, short* d3,
    short* d4, short* d5, short* d6) {
  const int y = blockIdx.y;
  const float* s;
  short* d;
  int n;
  switch (y) {
    case 0: s = s0; d = d0; n = BATCH * SEQ * DM; break;
    case 1: s = s1; d = d1; n = BATCH * SEQ * DM; break;
    case 2: s = s2; d = d2; n = BATCH * SEQ * DM; break;
    case 3: s = s3; d = d3; n = DM * DM; break;
    case 4: s = s4; d = d4; n = DM * DM; break;
    case 5: s = s5; d = d5; n = DM * DM; break;
    default: s = s6; d = d6; n = DM * DM; break;
  }
  const int n4 = n >> 2;
  const int stride = gridDim.x * 256;
  for (int i = blockIdx.x * 256 + threadIdx.x; i < n4; i += stride) {
    float4 v = ((const float4*)s)[i];
    uint2 o;
    o.x = pk2bf(v.x, v.y);
    o.y = pk2bf(v.z, v.w);
    ((uint2*)d)[i] = o;
  }
}

// ---------------------------------------------------------------------------
// Merged QKV projection: C = A @ W^T + bias, blockIdx.z selects {Q,K,V}.
//   z=0,1: bf16 head layout [B,H,S,DK] ; z=2: transposed [B,H,DK,S] (V)
// 128x128 tile, BK=64, 256 threads (4 waves 2x2), 4x4 frags/wave.
// ---------------------------------------------------------------------------
__global__ __launch_bounds__(256) void proj_qkv(
    const short* __restrict__ Aq, const short* __restrict__ Ak,
    const short* __restrict__ Av, const short* __restrict__ Wq_,
    const short* __restrict__ Wk_, const short* __restrict__ Wv_,
    const float* __restrict__ bq, const float* __restrict__ bk,
    const float* __restrict__ bv, short* __restrict__ Qh,
    short* __restrict__ Kh, short* __restrict__ Vt) {
  __shared__ short smem[128 * 136];
  short* As = smem;
  short* Ws = smem + 8192;

  const int z = blockIdx.z;
  const short* A = z == 0 ? Aq : z == 1 ? Ak : Av;
  const short* W = z == 0 ? Wq_ : z == 1 ? Wk_ : Wv_;
  const float* bias = z == 0 ? bq : z == 1 ? bk : bv;
  short* C = z == 0 ? Qh : z == 1 ? Kh : Vt;
  const bool tr = (z == 2);

  const int tid = threadIdx.x;
  const int wave = tid >> 6, lane = tid & 63;
  const int quad = lane >> 4, l15 = lane & 15;
  const int n0 = blockIdx.x * 128, m0 = blockIdx.y * 128;
  const int mh = (wave & 1) * 64, nh = (wave >> 1) * 64;
  const int ldr = lane >> 3, ldc = lane & 7;

  f32x4 acc[4][4] = {};

  for (int k0 = 0; k0 < 1024; k0 += 64) {
    __syncthreads();
#pragma unroll
    for (int i = 0; i < 8; ++i) {
      int seg = wave * 8 + i;
      int r = (seg & 15) * 8 + ldr;
      int kb = ldc ^ (r & 7);
      if (seg < 16)
        gload_lds16(&A[(size_t)(m0 + r) * 1024 + k0 + kb * 8], &As[seg * 512]);
      else
        gload_lds16(&W[(size_t)(n0 + r) * 1024 + k0 + kb * 8],
                    &Ws[(seg - 16) * 512]);
    }
    __syncthreads();
#pragma unroll
    for (int ks = 0; ks < 2; ++ks) {
      bf16x8 a[4], b[4];
      int kb = ks * 4 + quad;
#pragma unroll
      for (int f = 0; f < 4; ++f) {
        int rm = mh + f * 16 + l15;
        int rn = nh + f * 16 + l15;
        a[f] = *(const bf16x8*)&As[rm * 64 + (kb ^ (rm & 7)) * 8];
        b[f] = *(const bf16x8*)&Ws[rn * 64 + (kb ^ (rn & 7)) * 8];
      }
#pragma unroll
      for (int mf = 0; mf < 4; ++mf)
#pragma unroll
        for (int nf = 0; nf < 4; ++nf)
          acc[mf][nf] = __builtin_amdgcn_mfma_f32_16x16x32_bf16(
              a[mf], b[nf], acc[mf][nf], 0, 0, 0);
    }
  }

  float bvv[4];
#pragma unroll
  for (int nf = 0; nf < 4; ++nf) bvv[nf] = bias[n0 + nh + nf * 16 + l15];

  __syncthreads();
  short* Cb = smem;

  if (!tr) {
#pragma unroll
    for (int mf = 0; mf < 4; ++mf)
#pragma unroll
      for (int r = 0; r < 4; ++r) {
        int row = mh + mf * 16 + quad * 4 + r;
        unsigned u01 =
            pk2bf(acc[mf][0][r] + bvv[0], acc[mf][1][r] + bvv[1]);
        unsigned u23 =
            pk2bf(acc[mf][2][r] + bvv[2], acc[mf][3][r] + bvv[3]);
        Cb[row * 136 + nh + l15] = (short)u01;
        Cb[row * 136 + nh + 16 + l15] = (short)(u01 >> 16);
        Cb[row * 136 + nh + 32 + l15] = (short)u23;
        Cb[row * 136 + nh + 48 + l15] = (short)(u23 >> 16);
      }
    __syncthreads();
#pragma unroll
    for (int j = 0; j < 8; ++j) {
      int cid = tid + 256 * j;
      int row = cid >> 4, cb = cid & 15;
      bf16x8 v = *(const bf16x8*)&Cb[row * 136 + cb * 8];
      int m = m0 + row, n = n0 + cb * 8;
      int b = m >> 11, s = m & (SEQ - 1), h = n >> 6, d = n & 63;
      *(bf16x8*)&C[((size_t)(b * HEADS + h) * SEQ + s) * DK + d] = v;
    }
  } else {
#pragma unroll
    for (int mf = 0; mf < 4; ++mf)
#pragma unroll
      for (int nf = 0; nf < 4; ++nf) {
        unsigned u01 =
            pk2bf(acc[mf][nf][0] + bvv[nf], acc[mf][nf][1] + bvv[nf]);
        unsigned u23 =
            pk2bf(acc[mf][nf][2] + bvv[nf], acc[mf][nf][3] + bvv[nf]);
        int base_ = (nh + nf * 16 + l15) * 136 + mh + mf * 16 + quad * 4;
        *(unsigned*)&Cb[base_] = u01;
        *(unsigned*)&Cb[base_ + 2] = u23;
      }
    __syncthreads();
#pragma unroll
    for (int j = 0; j < 8; ++j) {
      int cid = tid + 256 * j;
      int row = cid >> 4, cb = cid & 15;
      bf16x8 v = *(const bf16x8*)&Cb[row * 136 + cb * 8];
      int n = n0 + row, m = m0 + cb * 8;
      int b = m >> 11, s = m & (SEQ - 1), h = n >> 6, d = n & 63;
      *(bf16x8*)&C[((size_t)(b * HEADS + h) * DK + d) * SEQ + s] = v;
    }
  }
}

// ---------------------------------------------------------------------------
// Output projection: fp32 out = concat @ Wo^T + bo.
// 128x64 tile (M x N), grid (16,32)=512 blocks -> 2 blocks/CU so barrier
// drains overlap across blocks. 4 waves: wave tile 64x32 (mf4 x nf2).
// ---------------------------------------------------------------------------
__global__ __launch_bounds__(256) void proj_out(const short* __restrict__ A,
                                                const short* __restrict__ W,
                                                const float* __restrict__ bias,
                                                float* __restrict__ C) {
  __shared__ short smem[12288];  // As 128x64 + Ws 64x64
  short* As = smem;
  short* Ws = smem + 8192;

  const int tid = threadIdx.x;
  const int wave = tid >> 6, lane = tid & 63;
  const int quad = lane >> 4, l15 = lane & 15;
  const int n0 = blockIdx.x * 64, m0 = blockIdx.y * 128;
  const int mh = (wave & 1) * 64, nh = (wave >> 1) * 32;
  const int ldr = lane >> 3, ldc = lane & 7;

  f32x4 acc[4][2] = {};

  for (int k0 = 0; k0 < 1024; k0 += 64) {
    __syncthreads();
#pragma unroll
    for (int i = 0; i < 6; ++i) {
      int seg = wave * 6 + i;  // 0..23: <16 A (128 rows), else W (64 rows)
      if (seg < 16) {
        int r = seg * 8 + ldr;
        int kb = ldc ^ (r & 7);
        gload_lds16(&A[(size_t)(m0 + r) * 1024 + k0 + kb * 8], &As[seg * 512]);
      } else {
        int r = (seg - 16) * 8 + ldr;
        int kb = ldc ^ (r & 7);
        gload_lds16(&W[(size_t)(n0 + r) * 1024 + k0 + kb * 8],
                    &Ws[(seg - 16) * 512]);
      }
    }
    __syncthreads();
#pragma unroll
    for (int ks = 0; ks < 2; ++ks) {
      bf16x8 a[4], b[2];
      int kb = ks * 4 + quad;
#pragma unroll
      for (int f = 0; f < 4; ++f) {
        int rm = mh + f * 16 + l15;
        a[f] = *(const bf16x8*)&As[rm * 64 + (kb ^ (rm & 7)) * 8];
      }
#pragma unroll
      for (int f = 0; f < 2; ++f) {
        int rn = nh + f * 16 + l15;
        b[f] = *(const bf16x8*)&Ws[rn * 64 + (kb ^ (rn & 7)) * 8];
      }
#pragma unroll
      for (int mf = 0; mf < 4; ++mf)
#pragma unroll
        for (int nf = 0; nf < 2; ++nf)
          acc[mf][nf] = __builtin_amdgcn_mfma_f32_16x16x32_bf16(
              a[mf], b[nf], acc[mf][nf], 0, 0, 0);
    }
  }

  float bvv[2];
#pragma unroll
  for (int nf = 0; nf < 2; ++nf) bvv[nf] = bias[n0 + nh + nf * 16 + l15];
#pragma unroll
  for (int mf = 0; mf < 4; ++mf)
#pragma unroll
    for (int nf = 0; nf < 2; ++nf)
#pragma unroll
      for (int r = 0; r < 4; ++r)
        C[(size_t)(m0 + mh + mf * 16 + quad * 4 + r) * 1024 + n0 + nh +
          nf * 16 + l15] = acc[mf][nf][r] + bvv[nf];
}

// ---------------------------------------------------------------------------
// Flash attention, bf16 MFMA, no-max softmax (scores |q.k|/8 bounded).
// Br=64 q-rows, 128 threads (2 waves x 32 rows), Bc=64 keys.
// Grid (S/64, B*H) = 1024 blocks -> 4 blocks/CU.
// K/V staging double-buffered: loads for kt+1 issued right after the tile-kt
// barrier -> barrier's vmcnt drain has a full tile of compute behind it.
// Key permutation pi(c)=2(c&15)+((c>>4)&1)+32(c>>5) on K-staging rows makes
// each lane's (nf,nf+1) P values slot-adjacent -> b32 pair writes; V keeps
// identity (slot s = key s), so PV contraction stays consistent.
// ---------------------------------------------------------------------------
__global__ __launch_bounds__(128) void attn_mfma(const short* __restrict__ Qh,
                                                 const short* __restrict__ Kh,
                                                 const short* __restrict__ VtG,
                                                 short* __restrict__ concat) {
  __shared__ short Ks[2][64 * 64];
  __shared__ short Vt[2][64 * 64];
  __shared__ short Ps[64 * 64];

  const int tid = threadIdx.x;
  const int wave = tid >> 6, lane = tid & 63;
  const int quad = lane >> 4, l15 = lane & 15;
  const int bh = blockIdx.y;
  const int q0 = blockIdx.x * 64;
  const size_t base = (size_t)bh * SEQ * DK;
  const int ldr = lane >> 3, ldc = lane & 7;

  // resident Q fragments (A-layout)
  bf16x8 qf[2][2];
#pragma unroll
  for (int mf = 0; mf < 2; ++mf)
#pragma unroll
    for (int ks = 0; ks < 2; ++ks)
      qf[mf][ks] =
          *(const bf16x8*)&Qh[base +
                              (size_t)(q0 + wave * 32 + mf * 16 + l15) * 64 +
                              ks * 32 + quad * 8];

  f32x4 O[2][4] = {};
  float lsum[2][4] = {};

  // staging helper data (4 segs of 8 rows per wave per tensor)
  // K row r holds global key pi(r); V row d is identity.
#define STAGE_TILE(kt_, buf_)                                              \
  {                                                                        \
    _Pragma("unroll") for (int i_ = 0; i_ < 4; ++i_) {                     \
      int seg = wave * 4 + i_;                                             \
      int row = seg * 8 + ldr;                                             \
      int kb = ldc ^ (row & 7);                                            \
      int key = 2 * (row & 15) + ((row >> 4) & 1) + 32 * (row >> 5);       \
      gload_lds16(&Kh[base + (size_t)((kt_)*64 + key) * 64 + kb * 8],      \
                  &Ks[buf_][seg * 512]);                                   \
      gload_lds16(&VtG[base + (size_t)row * SEQ + (kt_)*64 + kb * 8],      \
                  &Vt[buf_][seg * 512]);                                   \
    }                                                                      \
  }

  STAGE_TILE(0, 0);

  const float CE = 0.18033688011112042f;  // 0.125 * log2(e)

  for (int kt = 0; kt < SEQ / 64; ++kt) {
    const int cur = kt & 1;
    __syncthreads();  // drains buf[cur] loads; buf[cur^1] (kt-1) reads done
    if (kt + 1 < SEQ / 64) STAGE_TILE(kt + 1, cur ^ 1);

    // ---- S = Q.K^T (columns are pi-permuted keys) ----
    f32x4 sf[2][4] = {};
#pragma unroll
    for (int ks = 0; ks < 2; ++ks) {
      bf16x8 bfr[4];
      int kb = ks * 4 + quad;
#pragma unroll
      for (int nf = 0; nf < 4; ++nf) {
        int n = nf * 16 + l15;
        bfr[nf] = *(const bf16x8*)&Ks[cur][n * 64 + (kb ^ (n & 7)) * 8];
      }
#pragma unroll
      for (int mf = 0; mf < 2; ++mf)
#pragma unroll
        for (int nf = 0; nf < 4; ++nf)
          sf[mf][nf] = __builtin_amdgcn_mfma_f32_16x16x32_bf16(
              qf[mf][ks], bfr[nf], sf[mf][nf], 0, 0, 0);
    }

    // ---- exp2(|s|*C), accumulate l, pack pairs -> swizzled Ps ----
#pragma unroll
    for (int mf = 0; mf < 2; ++mf)
#pragma unroll
      for (int r = 0; r < 4; ++r) {
        float e0 = exp2f(fabsf(sf[mf][0][r]) * CE);
        float e1 = exp2f(fabsf(sf[mf][1][r]) * CE);
        float e2 = exp2f(fabsf(sf[mf][2][r]) * CE);
        float e3 = exp2f(fabsf(sf[mf][3][r]) * CE);
        lsum[mf][r] += (e0 + e1) + (e2 + e3);
        unsigned u01 = pk2bf(e0, e1);
        unsigned u23 = pk2bf(e2, e3);
        int row = wave * 32 + mf * 16 + quad * 4 + r;
        int sw = (row >> 1) & 7;
        int off = (2 * l15) & 7;
        short* rp = &Ps[row * 64];
        *(unsigned*)&rp[(((l15 >> 2) ^ sw) << 3) + off] = u01;
        *(unsigned*)&rp[(((4 + (l15 >> 2)) ^ sw) << 3) + off] = u23;
      }
    __threadfence_block();  // Ps rows are wave-private; order write->read

    // ---- O += P.V (slot s == key s) ----
#pragma unroll
    for (int ks = 0; ks < 2; ++ks) {
      bf16x8 av[2], bvv[4];
      int kb = ks * 4 + quad;
#pragma unroll
      for (int mf = 0; mf < 2; ++mf) {
        int row = wave * 32 + mf * 16 + l15;
        av[mf] =
            *(const bf16x8*)&Ps[row * 64 + ((kb ^ ((row >> 1) & 7)) << 3)];
      }
#pragma unroll
      for (int nf = 0; nf < 4; ++nf) {
        int n = nf * 16 + l15;  // d index
        bvv[nf] = *(const bf16x8*)&Vt[cur][n * 64 + (kb ^ (n & 7)) * 8];
      }
#pragma unroll
      for (int mf = 0; mf < 2; ++mf)
#pragma unroll
        for (int nf = 0; nf < 4; ++nf)
          O[mf][nf] = __builtin_amdgcn_mfma_f32_16x16x32_bf16(
              av[mf], bvv[nf], O[mf][nf], 0, 0, 0);
    }
  }

  // ---- reduce l over the 16 lanes sharing each row ----
  float inv[2][4];
#pragma unroll
  for (int mf = 0; mf < 2; ++mf)
#pragma unroll
    for (int r = 0; r < 4; ++r) {
      float s = lsum[mf][r];
#pragma unroll
      for (int x = 1; x < 16; x <<= 1) s += __shfl_xor(s, x, 64);
      inv[mf][r] = 1.f / s;
    }

  __syncthreads();  // all PV reads done before Ps reuse as O-staging
#pragma unroll
  for (int mf = 0; mf < 2; ++mf)
#pragma unroll
    for (int r = 0; r < 4; ++r) {
      unsigned u01 =
          pk2bf(O[mf][0][r] * inv[mf][r], O[mf][1][r] * inv[mf][r]);
      unsigned u23 =
          pk2bf(O[mf][2][r] * inv[mf][r], O[mf][3][r] * inv[mf][r]);
      int row = wave * 32 + mf * 16 + quad * 4 + r;
      int sw = (row >> 1) & 7;
      short* rp = &Ps[row * 64];
      // d columns are fixed by concat layout: scalar stores (once per block)
      rp[((((l15) >> 3) ^ sw) << 3) + (l15 & 7)] = (short)u01;
      rp[((((16 + l15) >> 3) ^ sw) << 3) + (l15 & 7)] = (short)(u01 >> 16);
      rp[((((32 + l15) >> 3) ^ sw) << 3) + (l15 & 7)] = (short)u23;
      rp[((((48 + l15) >> 3) ^ sw) << 3) + (l15 & 7)] = (short)(u23 >> 16);
    }
  __syncthreads();
  const int b = bh >> 4, h = bh & 15;
#pragma unroll
  for (int j = 0; j < 4; ++j) {
    int cid = tid + 128 * j;  // 64 rows x 8 chunks
    int row = cid >> 3, cb = cid & 7;
    bf16x8 v = *(const bf16x8*)&Ps[row * 64 + ((cb ^ ((row >> 1) & 7)) << 3)];
    *(bf16x8*)&concat[((size_t)(b * SEQ + q0 + row)) * DM + h * 64 + cb * 8] =
        v;
  }
#undef STAGE_TILE
}

extern "C" void kernel_launch(void* const* d_in, const int* in_sizes, int n_in,
                              void* d_out, int out_size, void* d_ws,
                              size_t ws_size, hipStream_t stream) {
  const float* q = (const float*)d_in[0];
  const float* k = (const float*)d_in[1];
  const float* v = (const float*)d_in[2];
  const float* Wq = (const float*)d_in[3];
  const float* bq = (const float*)d_in[4];
  const float* Wk = (const float*)d_in[5];
  const float* bk = (const float*)d_in[6];
  const float* Wv = (const float*)d_in[7];
  const float* bv = (const float*)d_in[8];
  const float* Wo = (const float*)d_in[9];
  const float* bo = (const float*)d_in[10];

  short* ws = (short*)d_ws;
  const size_t T4 = (size_t)BATCH * SEQ * DM;  // 4M elements
  const size_t T1 = (size_t)DM * DM;           // 1M elements
  short* qb = ws;
  short* kb_ = ws + T4;
  short* vb = ws + 2 * T4;
  short* Wqb = ws + 3 * T4;
  short* Wkb = Wqb + T1;
  short* Wvb = Wqb + 2 * T1;
  short* Wob = Wqb + 3 * T1;
  short* Qh = Wqb + 4 * T1;
  short* Kh = Qh + T4;
  short* VtG = Qh + 2 * T4;
  short* cc = Qh + 3 * T4;

  cvt7<<<dim3(1024, 7), 256, 0, stream>>>(q, k, v, Wq, Wk, Wv, Wo, qb, kb_, vb,
                                          Wqb, Wkb, Wvb, Wob);

  proj_qkv<<<dim3(DM / 128, (BATCH * SEQ) / 128, 3), 256, 0, stream>>>(
      qb, kb_, vb, Wqb, Wkb, Wvb, bq, bk, bv, Qh, Kh, VtG);

  attn_mfma<<<dim3(SEQ / 64, BATCH * HEADS), 128, 0, stream>>>(Qh, Kh, VtG,
                                                               cc);

  proj_out<<<dim3(DM / 64, (BATCH * SEQ) / 128), 256, 0, stream>>>(
      cc, Wob, bo, (float*)d_out);
}

// Round 5
// 254.820 us; speedup vs baseline: 1.0466x; 1.0466x over previous
//
#include <hip/hip_runtime.h>

#define HEADS 16
#define DK 64
#define DM 1024
#define SEQ 2048
#define BATCH 2

using bf16x8 = __attribute__((ext_vector_type(8))) short;
using short4v = __attribute__((ext_vector_type(4))) short;
using f32x4 = __attribute__((ext_vector_type(4))) float;

// fp32 -> bf16 bits, round-to-nearest-even (fallback path)
static __device__ __forceinline__ short f2bf(float x) {
  union { float f; unsigned u; } c;
  c.f = x;
  unsigned r = (c.u + 0x7FFFu + ((c.u >> 16) & 1u)) >> 16;
  return (short)r;
}

// pack two fp32 -> 2xbf16 in one u32 (lo = first).
static __device__ __forceinline__ unsigned pk2bf(float lo, float hi) {
#if __has_builtin(__builtin_amdgcn_cvt_pk_bf16_f32)
  auto t = __builtin_amdgcn_cvt_pk_bf16_f32(lo, hi);
  if constexpr (sizeof(t) == 4) {
    unsigned u;
    __builtin_memcpy(&u, &t, 4);
    return u;
  } else {
    return (unsigned)(unsigned short)f2bf(lo) |
           ((unsigned)(unsigned short)f2bf(hi) << 16);
  }
#else
  return (unsigned)(unsigned short)f2bf(lo) |
         ((unsigned)(unsigned short)f2bf(hi) << 16);
#endif
}

// async global->LDS, 16B per lane; LDS dest is wave-uniform base + lane*16
static __device__ __forceinline__ void gload_lds16(const void* g, void* l) {
  __builtin_amdgcn_global_load_lds(
      (const __attribute__((address_space(1))) void*)g,
      (__attribute__((address_space(3))) void*)l, 16, 0, 0);
}

// ---------------------------------------------------------------------------
// Bulk fp32 -> bf16 conversion for q,k,v and the 4 weight matrices.
// ---------------------------------------------------------------------------
__global__ __launch_bounds__(256) void cvt7(
    const float* __restrict__ s0, const float* __restrict__ s1,
    const float* __restrict__ s2, const float* __restrict__ s3,
    const float* __restrict__ s4, const float* __restrict__ s5,
    const float* __restrict__ s6, short* d0, short* d1, short* d2, short* d3,
    short* d4, short* d5, short* d6) {
  const int y = blockIdx.y;
  const float* s;
  short* d;
  int n;
  switch (y) {
    case 0: s = s0; d = d0; n = BATCH * SEQ * DM; break;
    case 1: s = s1; d = d1; n = BATCH * SEQ * DM; break;
    case 2: s = s2; d = d2; n = BATCH * SEQ * DM; break;
    case 3: s = s3; d = d3; n = DM * DM; break;
    case 4: s = s4; d = d4; n = DM * DM; break;
    case 5: s = s5; d = d5; n = DM * DM; break;
    default: s = s6; d = d6; n = DM * DM; break;
  }
  const int n4 = n >> 2;
  const int stride = gridDim.x * 256;
  for (int i = blockIdx.x * 256 + threadIdx.x; i < n4; i += stride) {
    float4 v = ((const float4*)s)[i];
    uint2 o;
    o.x = pk2bf(v.x, v.y);
    o.y = pk2bf(v.z, v.w);
    ((uint2*)d)[i] = o;
  }
}

// ---------------------------------------------------------------------------
// Merged QKV projection: C = A @ W^T + bias, blockIdx.z selects {Q,K,V}.
//   z=0,1: bf16 head layout [B,H,S,DK] ; z=2: transposed [B,H,DK,S] (V)
// 128x128 tile, BK=64, 256 threads (4 waves 2x2), 4x4 frags/wave.
// ---------------------------------------------------------------------------
__global__ __launch_bounds__(256) void proj_qkv(
    const short* __restrict__ Aq, const short* __restrict__ Ak,
    const short* __restrict__ Av, const short* __restrict__ Wq_,
    const short* __restrict__ Wk_, const short* __restrict__ Wv_,
    const float* __restrict__ bq, const float* __restrict__ bk,
    const float* __restrict__ bv, short* __restrict__ Qh,
    short* __restrict__ Kh, short* __restrict__ Vt) {
  __shared__ short smem[128 * 136];
  short* As = smem;
  short* Ws = smem + 8192;

  const int z = blockIdx.z;
  const short* A = z == 0 ? Aq : z == 1 ? Ak : Av;
  const short* W = z == 0 ? Wq_ : z == 1 ? Wk_ : Wv_;
  const float* bias = z == 0 ? bq : z == 1 ? bk : bv;
  short* C = z == 0 ? Qh : z == 1 ? Kh : Vt;
  const bool tr = (z == 2);

  const int tid = threadIdx.x;
  const int wave = tid >> 6, lane = tid & 63;
  const int quad = lane >> 4, l15 = lane & 15;
  const int n0 = blockIdx.x * 128, m0 = blockIdx.y * 128;
  const int mh = (wave & 1) * 64, nh = (wave >> 1) * 64;
  const int ldr = lane >> 3, ldc = lane & 7;

  f32x4 acc[4][4] = {};

  for (int k0 = 0; k0 < 1024; k0 += 64) {
    __syncthreads();
#pragma unroll
    for (int i = 0; i < 8; ++i) {
      int seg = wave * 8 + i;
      int r = (seg & 15) * 8 + ldr;
      int kb = ldc ^ (r & 7);
      if (seg < 16)
        gload_lds16(&A[(size_t)(m0 + r) * 1024 + k0 + kb * 8], &As[seg * 512]);
      else
        gload_lds16(&W[(size_t)(n0 + r) * 1024 + k0 + kb * 8],
                    &Ws[(seg - 16) * 512]);
    }
    __syncthreads();
#pragma unroll
    for (int ks = 0; ks < 2; ++ks) {
      bf16x8 a[4], b[4];
      int kb = ks * 4 + quad;
#pragma unroll
      for (int f = 0; f < 4; ++f) {
        int rm = mh + f * 16 + l15;
        int rn = nh + f * 16 + l15;
        a[f] = *(const bf16x8*)&As[rm * 64 + (kb ^ (rm & 7)) * 8];
        b[f] = *(const bf16x8*)&Ws[rn * 64 + (kb ^ (rn & 7)) * 8];
      }
#pragma unroll
      for (int mf = 0; mf < 4; ++mf)
#pragma unroll
        for (int nf = 0; nf < 4; ++nf)
          acc[mf][nf] = __builtin_amdgcn_mfma_f32_16x16x32_bf16(
              a[mf], b[nf], acc[mf][nf], 0, 0, 0);
    }
  }

  float bvv[4];
#pragma unroll
  for (int nf = 0; nf < 4; ++nf) bvv[nf] = bias[n0 + nh + nf * 16 + l15];

  __syncthreads();
  short* Cb = smem;

  if (!tr) {
#pragma unroll
    for (int mf = 0; mf < 4; ++mf)
#pragma unroll
      for (int r = 0; r < 4; ++r) {
        int row = mh + mf * 16 + quad * 4 + r;
        unsigned u01 =
            pk2bf(acc[mf][0][r] + bvv[0], acc[mf][1][r] + bvv[1]);
        unsigned u23 =
            pk2bf(acc[mf][2][r] + bvv[2], acc[mf][3][r] + bvv[3]);
        Cb[row * 136 + nh + l15] = (short)u01;
        Cb[row * 136 + nh + 16 + l15] = (short)(u01 >> 16);
        Cb[row * 136 + nh + 32 + l15] = (short)u23;
        Cb[row * 136 + nh + 48 + l15] = (short)(u23 >> 16);
      }
    __syncthreads();
#pragma unroll
    for (int j = 0; j < 8; ++j) {
      int cid = tid + 256 * j;
      int row = cid >> 4, cb = cid & 15;
      bf16x8 v = *(const bf16x8*)&Cb[row * 136 + cb * 8];
      int m = m0 + row, n = n0 + cb * 8;
      int b = m >> 11, s = m & (SEQ - 1), h = n >> 6, d = n & 63;
      *(bf16x8*)&C[((size_t)(b * HEADS + h) * SEQ + s) * DK + d] = v;
    }
  } else {
#pragma unroll
    for (int mf = 0; mf < 4; ++mf)
#pragma unroll
      for (int nf = 0; nf < 4; ++nf) {
        unsigned u01 =
            pk2bf(acc[mf][nf][0] + bvv[nf], acc[mf][nf][1] + bvv[nf]);
        unsigned u23 =
            pk2bf(acc[mf][nf][2] + bvv[nf], acc[mf][nf][3] + bvv[nf]);
        int base_ = (nh + nf * 16 + l15) * 136 + mh + mf * 16 + quad * 4;
        *(unsigned*)&Cb[base_] = u01;
        *(unsigned*)&Cb[base_ + 2] = u23;
      }
    __syncthreads();
#pragma unroll
    for (int j = 0; j < 8; ++j) {
      int cid = tid + 256 * j;
      int row = cid >> 4, cb = cid & 15;
      bf16x8 v = *(const bf16x8*)&Cb[row * 136 + cb * 8];
      int n = n0 + row, m = m0 + cb * 8;
      int b = m >> 11, s = m & (SEQ - 1), h = n >> 6, d = n & 63;
      *(bf16x8*)&C[((size_t)(b * HEADS + h) * DK + d) * SEQ + s] = v;
    }
  }
}

// ---------------------------------------------------------------------------
// Output projection: fp32 out = concat @ Wo^T + bo.
// 128x64 tile (M x N), grid (16,32)=512 blocks -> 2 blocks/CU.
// ---------------------------------------------------------------------------
__global__ __launch_bounds__(256) void proj_out(const short* __restrict__ A,
                                                const short* __restrict__ W,
                                                const float* __restrict__ bias,
                                                float* __restrict__ C) {
  __shared__ short smem[12288];  // As 128x64 + Ws 64x64
  short* As = smem;
  short* Ws = smem + 8192;

  const int tid = threadIdx.x;
  const int wave = tid >> 6, lane = tid & 63;
  const int quad = lane >> 4, l15 = lane & 15;
  const int n0 = blockIdx.x * 64, m0 = blockIdx.y * 128;
  const int mh = (wave & 1) * 64, nh = (wave >> 1) * 32;
  const int ldr = lane >> 3, ldc = lane & 7;

  f32x4 acc[4][2] = {};

  for (int k0 = 0; k0 < 1024; k0 += 64) {
    __syncthreads();
#pragma unroll
    for (int i = 0; i < 6; ++i) {
      int seg = wave * 6 + i;  // 0..23: <16 A (128 rows), else W (64 rows)
      if (seg < 16) {
        int r = seg * 8 + ldr;
        int kb = ldc ^ (r & 7);
        gload_lds16(&A[(size_t)(m0 + r) * 1024 + k0 + kb * 8], &As[seg * 512]);
      } else {
        int r = (seg - 16) * 8 + ldr;
        int kb = ldc ^ (r & 7);
        gload_lds16(&W[(size_t)(n0 + r) * 1024 + k0 + kb * 8],
                    &Ws[(seg - 16) * 512]);
      }
    }
    __syncthreads();
#pragma unroll
    for (int ks = 0; ks < 2; ++ks) {
      bf16x8 a[4], b[2];
      int kb = ks * 4 + quad;
#pragma unroll
      for (int f = 0; f < 4; ++f) {
        int rm = mh + f * 16 + l15;
        a[f] = *(const bf16x8*)&As[rm * 64 + (kb ^ (rm & 7)) * 8];
      }
#pragma unroll
      for (int f = 0; f < 2; ++f) {
        int rn = nh + f * 16 + l15;
        b[f] = *(const bf16x8*)&Ws[rn * 64 + (kb ^ (rn & 7)) * 8];
      }
#pragma unroll
      for (int mf = 0; mf < 4; ++mf)
#pragma unroll
        for (int nf = 0; nf < 2; ++nf)
          acc[mf][nf] = __builtin_amdgcn_mfma_f32_16x16x32_bf16(
              a[mf], b[nf], acc[mf][nf], 0, 0, 0);
    }
  }

  float bvv[2];
#pragma unroll
  for (int nf = 0; nf < 2; ++nf) bvv[nf] = bias[n0 + nh + nf * 16 + l15];
#pragma unroll
  for (int mf = 0; mf < 4; ++mf)
#pragma unroll
    for (int nf = 0; nf < 2; ++nf)
#pragma unroll
      for (int r = 0; r < 4; ++r)
        C[(size_t)(m0 + mh + mf * 16 + quad * 4 + r) * 1024 + n0 + nh +
          nf * 16 + l15] = acc[mf][nf][r] + bvv[nf];
}

// ---------------------------------------------------------------------------
// Flash attention, bf16 MFMA, no-max softmax (scores |q.k|/8 bounded).
// Br=64 q-rows, 256 threads = 4 waves x 16 rows, Bc=64 keys.
// Grid (S/64, B*H) = 1024 blocks -> 4 blocks/CU, 16 waves/CU (2x R3's
// latency hiding). LDS formulas identical to R3's measured-conflict-free
// scheme (Ks/Vt chunk-xor staging, Ps chunk-xor by (row>>1)&7, b16 P writes).
// ---------------------------------------------------------------------------
__global__ __launch_bounds__(256) void attn_mfma(const short* __restrict__ Qh,
                                                 const short* __restrict__ Kh,
                                                 const short* __restrict__ VtG,
                                                 short* __restrict__ concat) {
  __shared__ short Ks[64 * 64];  // swizzled packed [key][dchunk]
  __shared__ short Vt[64 * 64];  // swizzled packed [d][keychunk]
  __shared__ short Ps[64 * 64];  // swizzled packed [qrow][keychunk]

  const int tid = threadIdx.x;
  const int wave = tid >> 6, lane = tid & 63;
  const int quad = lane >> 4, l15 = lane & 15;
  const int bh = blockIdx.y;
  const int q0 = blockIdx.x * 64;
  const size_t base = (size_t)bh * SEQ * DK;
  const int ldr = lane >> 3, ldc = lane & 7;

  // resident Q fragments (A-layout): rows q0 + wave*16 + l15
  bf16x8 qf[2];
#pragma unroll
  for (int ks = 0; ks < 2; ++ks)
    qf[ks] = *(const bf16x8*)&Qh[base + (size_t)(q0 + wave * 16 + l15) * 64 +
                                 ks * 32 + quad * 8];

  f32x4 O[4] = {};
  float lsum[4] = {};

  const float CE = 0.18033688011112042f;  // 0.125 * log2(e)

  for (int kt = 0; kt < SEQ / 64; ++kt) {
    __syncthreads();
#pragma unroll
    for (int i = 0; i < 2; ++i) {
      int seg = wave * 2 + i;  // 0..7, 8 rows each
      int row = seg * 8 + ldr;
      int kb = ldc ^ (row & 7);
      gload_lds16(&Kh[base + (size_t)(kt * 64 + row) * 64 + kb * 8],
                  &Ks[seg * 512]);
      gload_lds16(&VtG[base + (size_t)row * SEQ + kt * 64 + kb * 8],
                  &Vt[seg * 512]);
    }
    __syncthreads();

    // ---- S = Q.K^T ----
    f32x4 sf[4] = {};
#pragma unroll
    for (int ks = 0; ks < 2; ++ks) {
      bf16x8 bfr[4];
      int kb = ks * 4 + quad;
#pragma unroll
      for (int nf = 0; nf < 4; ++nf) {
        int n = nf * 16 + l15;
        bfr[nf] = *(const bf16x8*)&Ks[n * 64 + (kb ^ (n & 7)) * 8];
      }
#pragma unroll
      for (int nf = 0; nf < 4; ++nf)
        sf[nf] = __builtin_amdgcn_mfma_f32_16x16x32_bf16(qf[ks], bfr[nf],
                                                         sf[nf], 0, 0, 0);
    }

    // ---- exp2(|s|*C), accumulate l, P -> swizzled Ps (b16, R3 scheme) ----
    const int h2 = l15 >> 3, lo3 = l15 & 7;
#pragma unroll
    for (int r = 0; r < 4; ++r) {
      float e0 = exp2f(fabsf(sf[0][r]) * CE);
      float e1 = exp2f(fabsf(sf[1][r]) * CE);
      float e2 = exp2f(fabsf(sf[2][r]) * CE);
      float e3 = exp2f(fabsf(sf[3][r]) * CE);
      lsum[r] += (e0 + e1) + (e2 + e3);
      unsigned u01 = pk2bf(e0, e1);
      unsigned u23 = pk2bf(e2, e3);
      int row = wave * 16 + quad * 4 + r;
      int sw = (row >> 1) & 7;
      short* rp = &Ps[row * 64];
      rp[(((0 + h2) ^ sw) << 3) + lo3] = (short)u01;
      rp[(((2 + h2) ^ sw) << 3) + lo3] = (short)(u01 >> 16);
      rp[(((4 + h2) ^ sw) << 3) + lo3] = (short)u23;
      rp[(((6 + h2) ^ sw) << 3) + lo3] = (short)(u23 >> 16);
    }
    __threadfence_block();  // Ps rows are wave-private; order write->read

    // ---- O += P.V ----
#pragma unroll
    for (int ks = 0; ks < 2; ++ks) {
      bf16x8 av, bvv[4];
      int kb = ks * 4 + quad;
      int row = wave * 16 + l15;
      av = *(const bf16x8*)&Ps[row * 64 + ((kb ^ ((row >> 1) & 7)) << 3)];
#pragma unroll
      for (int nf = 0; nf < 4; ++nf) {
        int n = nf * 16 + l15;  // d index
        bvv[nf] = *(const bf16x8*)&Vt[n * 64 + (kb ^ (n & 7)) * 8];
      }
#pragma unroll
      for (int nf = 0; nf < 4; ++nf)
        O[nf] = __builtin_amdgcn_mfma_f32_16x16x32_bf16(av, bvv[nf], O[nf], 0,
                                                        0, 0);
    }
  }

  // ---- reduce l over the 16 lanes sharing each row ----
  float inv[4];
#pragma unroll
  for (int r = 0; r < 4; ++r) {
    float s = lsum[r];
#pragma unroll
    for (int x = 1; x < 16; x <<= 1) s += __shfl_xor(s, x, 64);
    inv[r] = 1.f / s;
  }

  __syncthreads();  // all PV reads done before Ps reuse as O-staging
  const int h2 = l15 >> 3, lo3 = l15 & 7;
#pragma unroll
  for (int r = 0; r < 4; ++r) {
    unsigned u01 = pk2bf(O[0][r] * inv[r], O[1][r] * inv[r]);
    unsigned u23 = pk2bf(O[2][r] * inv[r], O[3][r] * inv[r]);
    int row = wave * 16 + quad * 4 + r;
    int sw = (row >> 1) & 7;
    short* rp = &Ps[row * 64];
    rp[(((0 + h2) ^ sw) << 3) + lo3] = (short)u01;
    rp[(((2 + h2) ^ sw) << 3) + lo3] = (short)(u01 >> 16);
    rp[(((4 + h2) ^ sw) << 3) + lo3] = (short)u23;
    rp[(((6 + h2) ^ sw) << 3) + lo3] = (short)(u23 >> 16);
  }
  __syncthreads();
  const int b = bh >> 4, h = bh & 15;
#pragma unroll
  for (int j = 0; j < 2; ++j) {
    int cid = tid + 256 * j;  // 64 rows x 8 chunks
    int row = cid >> 3, cb = cid & 7;
    bf16x8 v = *(const bf16x8*)&Ps[row * 64 + ((cb ^ ((row >> 1) & 7)) << 3)];
    *(bf16x8*)&concat[((size_t)(b * SEQ + q0 + row)) * DM + h * 64 + cb * 8] =
        v;
  }
}

extern "C" void kernel_launch(void* const* d_in, const int* in_sizes, int n_in,
                              void* d_out, int out_size, void* d_ws,
                              size_t ws_size, hipStream_t stream) {
  const float* q = (const float*)d_in[0];
  const float* k = (const float*)d_in[1];
  const float* v = (const float*)d_in[2];
  const float* Wq = (const float*)d_in[3];
  const float* bq = (const float*)d_in[4];
  const float* Wk = (const float*)d_in[5];
  const float* bk = (const float*)d_in[6];
  const float* Wv = (const float*)d_in[7];
  const float* bv = (const float*)d_in[8];
  const float* Wo = (const float*)d_in[9];
  const float* bo = (const float*)d_in[10];

  short* ws = (short*)d_ws;
  const size_t T4 = (size_t)BATCH * SEQ * DM;  // 4M elements
  const size_t T1 = (size_t)DM * DM;           // 1M elements
  short* qb = ws;
  short* kb_ = ws + T4;
  short* vb = ws + 2 * T4;
  short* Wqb = ws + 3 * T4;
  short* Wkb = Wqb + T1;
  short* Wvb = Wqb + 2 * T1;
  short* Wob = Wqb + 3 * T1;
  short* Qh = Wqb + 4 * T1;
  short* Kh = Qh + T4;
  short* VtG = Qh + 2 * T4;
  short* cc = Qh + 3 * T4;

  cvt7<<<dim3(1024, 7), 256, 0, stream>>>(q, k, v, Wq, Wk, Wv, Wo, qb, kb_, vb,
                                          Wqb, Wkb, Wvb, Wob);

  proj_qkv<<<dim3(DM / 128, (BATCH * SEQ) / 128, 3), 256, 0, stream>>>(
      qb, kb_, vb, Wqb, Wkb, Wvb, bq, bk, bv, Qh, Kh, VtG);

  attn_mfma<<<dim3(SEQ / 64, BATCH * HEADS), 256, 0, stream>>>(Qh, Kh, VtG,
                                                               cc);

  proj_out<<<dim3(DM / 64, (BATCH * SEQ) / 128), 256, 0, stream>>>(
      cc, Wob, bo, (float*)d_out);
}